// Round 3
// baseline (49.507 us; speedup 1.0000x reference)
//
#include <hip/hip_runtime.h>
#include <hip/hip_bf16.h>

// MyDeConv1D: dilated transposed-conv scatter, recast as GEMM + epilogue.
// out[b,t,f] = sum_{j=0..7,c} x[b, t+28-4j, c] * W[c,j,f]  (rows >= T are zero)
//            + cnt(t) * 256 * bias[f]
// GEMM: M=B*T=32768, N=F=256, K=C*KT=2048 -> bf16 MFMA 16x16x32.
// R3: MF=8 rows-per-wave (halves W L2 re-read to 256 MB), 512-thr blocks,
//     BT=128, NF=2 per wave; wprep write-coalesced.

#define B_    16
#define T_    2048
#define C_    256
#define KT    8
#define F_    256
#define DILL  4
#define SH    28          // (KT-1)*DILL
#define BT    128         // t-rows per block
#define ROWS  (BT + SH)   // 156 staged x rows

typedef __attribute__((ext_vector_type(8))) short short8;
typedef __attribute__((ext_vector_type(4))) float floatx4;

// W[c][j][f] f32 -> Wf fragment order: frag (j,cs,g), lane holds
// B[k=q*8+i][n=l16] for f=g*16+l16, c=cs*32+q*8+i. 1KB/frag contiguous.
// Reads scattered 4B (L2-served, W is 2MB), writes coalesced 16B/lane.
__global__ __launch_bounds__(256) void wprep_kernel(const float* __restrict__ W,
                                                    ushort* __restrict__ Wf) {
    const int tid  = threadIdx.x;
    const int fid  = blockIdx.x * 4 + (tid >> 6);   // fragment id 0..1023
    const int lane = tid & 63;
    const int g    = fid & 15;
    const int cs   = (fid >> 4) & 7;
    const int j    = fid >> 7;
    const int c0   = cs * 32 + (lane >> 4) * 8;
    const int f    = g * 16 + (lane & 15);
    short8 pk;
    #pragma unroll
    for (int i = 0; i < 8; ++i) {
        __hip_bfloat16 h = __float2bfloat16(W[((c0 + i) * KT + j) * F_ + f]);
        pk[i] = *reinterpret_cast<const short*>(&h);
    }
    *reinterpret_cast<short8*>(Wf + fid * 512 + lane * 8) = pk;
}

__global__ __launch_bounds__(512, 2) void deconv_kernel(
        const float* __restrict__ x, const ushort* __restrict__ Wf,
        const float* __restrict__ bias, float* __restrict__ out) {
    __shared__ ushort xs[ROWS * C_];           // 156*256 bf16 = 78 KiB
    const int t0  = blockIdx.x * BT;
    const int b   = blockIdx.y;
    const int tid = threadIdx.x;

    // ---- stage x[t0 .. t0+ROWS) -> bf16 LDS, 16B chunks XOR-swizzled by row ----
    for (int idx = tid; idx < ROWS * 32; idx += 512) {
        const int row = idx >> 5, cb = idx & 31;
        const int t = t0 + row;
        float v[8] = {0.f,0.f,0.f,0.f,0.f,0.f,0.f,0.f};
        if (t < T_) {
            const float4* p = reinterpret_cast<const float4*>(
                x + ((b * T_ + t) * C_ + cb * 8));
            float4 u0 = p[0], u1 = p[1];
            v[0]=u0.x; v[1]=u0.y; v[2]=u0.z; v[3]=u0.w;
            v[4]=u1.x; v[5]=u1.y; v[6]=u1.z; v[7]=u1.w;
        }
        short8 pk;
        #pragma unroll
        for (int i = 0; i < 8; ++i) {
            __hip_bfloat16 h = __float2bfloat16(v[i]);
            pk[i] = *reinterpret_cast<const short*>(&h);
        }
        const int sc = cb ^ (row & 7);
        *reinterpret_cast<short8*>(&xs[row * C_ + sc * 8]) = pk;
    }

    const int lane = tid & 63, wave = tid >> 6;   // 8 waves, wave owns f[w*32,w*32+32)
    const int l16 = lane & 15, q = lane >> 4;

    float bf2[2];
    #pragma unroll
    for (int nf = 0; nf < 2; ++nf) bf2[nf] = bias[wave * 32 + nf * 16 + l16];

    __syncthreads();

    floatx4 acc[8][2];
    #pragma unroll
    for (int mf = 0; mf < 8; ++mf)
        #pragma unroll
        for (int nf = 0; nf < 2; ++nf)
            acc[mf][nf] = (floatx4){0.f, 0.f, 0.f, 0.f};

    const ushort* wbase = Wf + wave * 1024 + lane * 8;   // + s*8192 + nf*512

#define LOAD_A(s_, arr) do {                                              \
        const int j_ = (s_) >> 3, cs_ = (s_) & 7;                         \
        const int shift_ = SH - 4 * j_;                                   \
        _Pragma("unroll")                                                 \
        for (int mf = 0; mf < 8; ++mf) {                                  \
            const int row_ = mf * 16 + l16 + shift_;                      \
            const int ch_  = ((cs_ << 2) + q) ^ (row_ & 7);               \
            arr[mf] = *reinterpret_cast<const short8*>(                   \
                &xs[row_ * C_ + ch_ * 8]);                                \
        } } while (0)

#define LOAD_B(s_, arr) do {                                              \
        const ushort* p_ = wbase + (s_) * 8192;                           \
        _Pragma("unroll")                                                 \
        for (int nf = 0; nf < 2; ++nf)                                    \
            arr[nf] = *reinterpret_cast<const short8*>(p_ + nf * 512);    \
        } while (0)

#define DO_MFMA(aa, bb) do {                                              \
        _Pragma("unroll")                                                 \
        for (int mf = 0; mf < 8; ++mf)                                    \
            _Pragma("unroll")                                             \
            for (int nf = 0; nf < 2; ++nf)                                \
                acc[mf][nf] = __builtin_amdgcn_mfma_f32_16x16x32_bf16(    \
                    aa[mf], bb[nf], acc[mf][nf], 0, 0, 0);                \
        } while (0)

    short8 a0[8], b0[2], a1[8], b1[2];
    LOAD_A(0, a0); LOAD_B(0, b0);
    LOAD_A(1, a1); LOAD_B(1, b1);

    for (int s = 0; s < 64; s += 2) {
        DO_MFMA(a0, b0);
        const int sp2 = (s + 2) & 63;        // wraps harmlessly on last iter
        LOAD_A(sp2, a0); LOAD_B(sp2, b0);
        DO_MFMA(a1, b1);
        const int sp3 = (s + 3) & 63;
        LOAD_A(sp3, a1); LOAD_B(sp3, b1);
    }

    // ---- epilogue: + cnt(t) * C * bias[f];  C/D map row=(q*4+r), col=l16 ----
    #pragma unroll
    for (int nf = 0; nf < 2; ++nf) {
        const int f = wave * 32 + nf * 16 + l16;
        #pragma unroll
        for (int mf = 0; mf < 8; ++mf) {
            #pragma unroll
            for (int r = 0; r < 4; ++r) {
                const int t = t0 + mf * 16 + q * 4 + r;
                const int jmin = (t < T_ - SH) ? 0 : (((t - (T_ - SH)) >> 2) + 1);
                out[(b * T_ + t) * F_ + f] =
                    acc[mf][nf][r] + (float)(8 - jmin) * 256.0f * bf2[nf];
            }
        }
    }
#undef LOAD_A
#undef LOAD_B
#undef DO_MFMA
}

extern "C" void kernel_launch(void* const* d_in, const int* in_sizes, int n_in,
                              void* d_out, int out_size, void* d_ws, size_t ws_size,
                              hipStream_t stream) {
    const float* x    = (const float*)d_in[0];
    const float* W    = (const float*)d_in[1];   // (C,KT,F)
    const float* bias = (const float*)d_in[2];
    float* out = (float*)d_out;
    ushort* Wf = (ushort*)d_ws;                  // KT*F*C bf16 = 1 MiB scratch

    wprep_kernel<<<256, 256, 0, stream>>>(W, Wf);
    dim3 grid(T_ / BT, B_);
    deconv_kernel<<<grid, 512, 0, stream>>>(x, Wf, bias, out);
}